// Round 4
// baseline (1083.261 us; speedup 1.0000x reference)
//
#include <hip/hip_runtime.h>
#include <math.h>

#define NPFS   4
#define NFM    512
#define NP     256
#define BATCH  128
#define NBLK   (BATCH * NPFS)   // 512 pfaffians
#define THREADS 1024
#define NWAVES (THREADS / 64)
#define TRI    ((NP * (NP - 1)) / 2)   // 32640 strict-lower elements
#define NB     4                 // steps per panel block -> rank-8 trailing update
#define BSTEPS (2 * NB)          // 8 columns consumed per block
#define LFLOATS 33024            // padded strict-lower triangle, floats

// fp32 packed strict-lower triangle, each row padded to a multiple of 4
// floats so every row starts 16B-aligned. rowoff(256) = 33024 floats.
__device__ __forceinline__ int rowoff(int r) {
    int q = r >> 2, rem = r & 3;
    int g = 2 * q * q + q;
    if (rem > 0) g += q;
    if (rem > 1) g += q + 1;
    if (rem > 2) g += q + 1;
    return g << 2;
}

// ====================================================================
// Main version: L triangle in GLOBAL workspace (L2/L3-resident), only
// tau/v panels in LDS (17 KB) -> 2 blocks/CU co-resident -> the whole
// 512-block grid runs concurrently (no second sequential pass).
// ====================================================================
extern "C" __global__ __launch_bounds__(THREADS, 8)
void MultiPf_32469952758284_kernel(const float* __restrict__ F,
                                   const int* __restrict__ idx,
                                   float* ws)
{
    __shared__ float Tcol[NB * NP];    // tau_j, col-major
    __shared__ float Vcol[NB * NP];    // v_j, col-major
    __shared__ float TVrow[NP * 8];    // row-major dup: t0..3,v0..3
    __shared__ int   idxL[NP];

    const int tid = threadIdx.x;
    const int bid = blockIdx.x;
    const int b = bid >> 2;   // batch
    const int s = bid & 3;    // pf-state
    const float* __restrict__ Fs = F + (size_t)s * NFM * NFM;
    // per-block L region; ws[0..1024) reserved for results
    float* Lg = ws + 1024 + (size_t)bid * LFLOATS;

    if (tid < NP) idxL[tid] = idx[b * NP + tid];
    __syncthreads();

    // ---- gather strict lower triangle: A[r][c] = 0.5*(F[ir][ic] - F[ic][ir])
    for (int e = tid; e < TRI; e += THREADS) {
        int r = (int)((1.0f + sqrtf(1.0f + 8.0f * (float)e)) * 0.5f);
        while (r * (r - 1) / 2 > e) --r;
        while (r * (r + 1) / 2 <= e) ++r;
        int c = e - r * (r - 1) / 2;
        int ir = idxL[r], ic = idxL[c];
        float val = 0.5f * (Fs[(size_t)ir * NFM + ic] - Fs[(size_t)ic * NFM + ir]);
        Lg[rowoff(r) + c] = val;
    }

    float sgn = 1.0f, la = 0.0f;   // maintained on wave 0; tid 0 writes out
    __syncthreads();

    for (int kb = 0; kb < NP / BSTEPS; ++kb) {
        const int k0 = kb * BSTEPS;

        // ========== panel: NB steps, single wave, no __syncthreads ==========
        if (tid < 64) {
            const int lane = tid;
            for (int j = 0; j < NB; ++j) {
                const int k = k0 + 2 * j;
                const int p = k + 1;

                // fence: prev step's Tcol/Vcol (LDS) and Lg (global) writes
                // by other lanes of this wave must be visible.
                asm volatile("s_waitcnt vmcnt(0) lgkmcnt(0)" ::: "memory");
                __builtin_amdgcn_sched_barrier(0);

                // uniform panel values at row k (valid: k >= k_jj+2 for jj<j)
                float tk0 = 0.f, vk0 = 0.f, tk1 = 0.f, vk1 = 0.f, tk2 = 0.f, vk2 = 0.f;
                if (j > 0) { tk0 = Tcol[0 * NP + k]; vk0 = Vcol[0 * NP + k]; }
                if (j > 1) { tk1 = Tcol[1 * NP + k]; vk1 = Vcol[1 * NP + k]; }
                if (j > 2) { tk2 = Tcol[2 * NP + k]; vk2 = Vcol[2 * NP + k]; }

                // A1: refresh pivot column k into registers (no write-back:
                // column k is consumed after this step).
                float x[4];
                #pragma unroll
                for (int ii = 0; ii < 4; ++ii) {
                    const int r = lane + 64 * ii;
                    x[ii] = 0.0f;
                    if (r > k) {
                        const int orr = rowoff(r);
                        float xv = Lg[orr + k];
                        if (j > 0) xv += Vcol[0 * NP + r] * tk0 - Tcol[0 * NP + r] * vk0;
                        if (j > 1) xv += Vcol[1 * NP + r] * tk1 - Tcol[1 * NP + r] * vk1;
                        if (j > 2) xv += Vcol[2 * NP + r] * tk2 - Tcol[2 * NP + r] * vk2;
                        x[ii] = xv;
                    }
                }

                // argmax_{r>k} |x[r]|, tie -> lowest r (matches jnp.argmax).
                // key = (|x|<<32) | ((255-r)<<1) | signbit : sign below index
                // bits so ties resolve purely by index; winner's float bits
                // are reconstructed exactly from the key.
                unsigned long long key = 0ull;
                #pragma unroll
                for (int ii = 0; ii < 4; ++ii) {
                    const int r = lane + 64 * ii;
                    if (r > k) {
                        const unsigned int bits = __float_as_uint(x[ii]);
                        const unsigned int ab = bits & 0x7fffffffu;
                        const unsigned long long kk =
                            ((unsigned long long)ab << 32) |
                            ((unsigned)(NP - 1 - r) << 1) | (bits >> 31);
                        if (kk > key) key = kk;
                    }
                }
                #pragma unroll
                for (int o = 1; o < 64; o <<= 1) {
                    const unsigned long long ok = __shfl_xor(key, o);
                    if (ok > key) key = ok;
                }
                const int kp = (NP - 1) - (int)((key >> 1) & 0xffu);
                const unsigned int csb =
                    (unsigned int)(key >> 32) | ((unsigned int)(key & 1u) << 31);
                const float cs = __uint_as_float(csb);
                const float piv = -cs;          // piv = A_post[k][k+1] = -L_pre[kp][k]
                const float rpiv = 1.0f / piv;
                if (kp != p) sgn = -sgn;
                if (piv < 0.0f) sgn = -sgn;
                la += logf(fabsf(piv));

                // refreshed col-k value at row p -> row kp's tau after swap
                const int slot = p >> 6, sl = p & 63;
                const float xsel = (slot == 0) ? x[0] : (slot == 1) ? x[1]
                                  : (slot == 2) ? x[2] : x[3];
                const float xp = __shfl(xsel, sl);

                // uniform panel values at post-swap row p (= pre-swap row kp)
                float tp0 = 0.f, vp0 = 0.f, tp1 = 0.f, vp1 = 0.f, tp2 = 0.f, vp2 = 0.f;
                if (j > 0) { tp0 = Tcol[0 * NP + kp]; vp0 = Vcol[0 * NP + kp]; }
                if (j > 1) { tp1 = Tcol[1 * NP + kp]; vp1 = Vcol[1 * NP + kp]; }
                if (j > 2) { tp2 = Tcol[2 * NP + kp]; vp2 = Vcol[2 * NP + kp]; }

                // P2: symmetric swap (p<->kp) on L; capture post-swap column p.
                // Each (row,element) touched by exactly one lane -> race-free.
                float vsw[4];
                #pragma unroll
                for (int ii = 0; ii < 4; ++ii) vsw[ii] = 0.0f;
                if (kp == p) {
                    #pragma unroll
                    for (int ii = 0; ii < 4; ++ii) {
                        const int r = lane + 64 * ii;
                        if (r >= k + 2) vsw[ii] = Lg[rowoff(r) + p];
                    }
                } else {
                    const int okp = rowoff(kp);
                    #pragma unroll
                    for (int ii = 0; ii < 4; ++ii) {
                        const int r = lane + 64 * ii;
                        if (r >= k + 2) {
                            const int orr = rowoff(r);
                            if (r < kp) {
                                float a0 = Lg[orr + p], a1 = Lg[okp + r];
                                Lg[orr + p] = -a1; Lg[okp + r] = -a0;
                                vsw[ii] = -a1;
                            } else if (r == kp) {
                                float wv = -Lg[orr + p];
                                Lg[orr + p] = wv; vsw[ii] = wv;
                            } else { // r > kp
                                float t = Lg[orr + p], u2 = Lg[orr + kp];
                                Lg[orr + p] = u2; Lg[orr + kp] = t;
                                vsw[ii] = u2;
                            }
                        }
                    }
                    // physical swap of rows p,kp in accumulated panels (jj<j)
                    if (lane < j) {
                        const int jj = lane;
                        float a, b2;
                        a = Tcol[jj * NP + p]; b2 = Tcol[jj * NP + kp];
                        Tcol[jj * NP + p] = b2; Tcol[jj * NP + kp] = a;
                        a = Vcol[jj * NP + p]; b2 = Vcol[jj * NP + kp];
                        Vcol[jj * NP + p] = b2; Vcol[jj * NP + kp] = a;
                        a = TVrow[p * 8 + jj]; b2 = TVrow[kp * 8 + jj];
                        TVrow[p * 8 + jj] = b2; TVrow[kp * 8 + jj] = a;
                        a = TVrow[p * 8 + 4 + jj]; b2 = TVrow[kp * 8 + 4 + jj];
                        TVrow[p * 8 + 4 + jj] = b2; TVrow[kp * 8 + 4 + jj] = a;
                    }
                }
                asm volatile("s_waitcnt lgkmcnt(0)" ::: "memory");
                __builtin_amdgcn_sched_barrier(0);

                // A2: refresh column p + extract tau/v into panel slot j.
                #pragma unroll
                for (int ii = 0; ii < 4; ++ii) {
                    const int r = lane + 64 * ii;
                    if (r >= k + 2) {
                        const float xpost = (r == kp) ? xp : x[ii];
                        const float tau = xpost * rpiv;
                        float y = vsw[ii];
                        if (j > 0) y += Vcol[0 * NP + r] * tp0 - Tcol[0 * NP + r] * vp0;
                        if (j > 1) y += Vcol[1 * NP + r] * tp1 - Tcol[1 * NP + r] * vp1;
                        if (j > 2) y += Vcol[2 * NP + r] * tp2 - Tcol[2 * NP + r] * vp2;
                        Tcol[j * NP + r] = tau;
                        Vcol[j * NP + r] = y;
                        TVrow[r * 8 + j] = tau;
                        TVrow[r * 8 + 4 + j] = y;
                    }
                }
            }
            // drain panel's global swap writes before releasing the barrier
            asm volatile("s_waitcnt vmcnt(0)" ::: "memory");
        }
        __syncthreads();   // panel results visible to all waves

        // ================= trailing rank-2*NB update =================
        // Lane owns 4 FIXED columns -> tau/v column values preloaded into
        // registers once per block. Per row: 1 float4 read + 1 float4 write
        // of Lg (coalesced) + 2 uniform LDS broadcasts (TVrow).
        const int kend = k0 + BSTEPS;   // multiple of 8 -> 16B aligned
        if (kend < NP) {
            const int w = tid >> 6;
            const int lane = tid & 63;
            const int c0 = kend + (lane << 2);
            float4 tj0 = {0,0,0,0}, tj1 = {0,0,0,0}, tj2 = {0,0,0,0}, tj3 = {0,0,0,0};
            float4 vj0 = {0,0,0,0}, vj1 = {0,0,0,0}, vj2 = {0,0,0,0}, vj3 = {0,0,0,0};
            if (c0 < NP) {
                tj0 = *(const float4*)(Tcol + 0 * NP + c0);
                tj1 = *(const float4*)(Tcol + 1 * NP + c0);
                tj2 = *(const float4*)(Tcol + 2 * NP + c0);
                tj3 = *(const float4*)(Tcol + 3 * NP + c0);
                vj0 = *(const float4*)(Vcol + 0 * NP + c0);
                vj1 = *(const float4*)(Vcol + 1 * NP + c0);
                vj2 = *(const float4*)(Vcol + 2 * NP + c0);
                vj3 = *(const float4*)(Vcol + 3 * NP + c0);
            }
            for (int r = kend + 1 + w; r < NP; r += NWAVES) {
                const float4 t4 = *(const float4*)(TVrow + r * 8);      // tau_j[r]
                const float4 v4 = *(const float4*)(TVrow + r * 8 + 4);  // v_j[r]
                if (c0 < r) {
                    float* Lp = Lg + rowoff(r) + c0;
                    float4 l = *(float4*)Lp;
                    // jj ascending: same per-element rounding chain as reference
                    l.x += v4.x * tj0.x - t4.x * vj0.x;
                    l.y += v4.x * tj0.y - t4.x * vj0.y;
                    l.z += v4.x * tj0.z - t4.x * vj0.z;
                    l.w += v4.x * tj0.w - t4.x * vj0.w;
                    l.x += v4.y * tj1.x - t4.y * vj1.x;
                    l.y += v4.y * tj1.y - t4.y * vj1.y;
                    l.z += v4.y * tj1.z - t4.y * vj1.z;
                    l.w += v4.y * tj1.w - t4.y * vj1.w;
                    l.x += v4.z * tj2.x - t4.z * vj2.x;
                    l.y += v4.z * tj2.y - t4.z * vj2.y;
                    l.z += v4.z * tj2.z - t4.z * vj2.z;
                    l.w += v4.z * tj2.w - t4.z * vj2.w;
                    l.x += v4.w * tj3.x - t4.w * vj3.x;
                    l.y += v4.w * tj3.y - t4.w * vj3.y;
                    l.z += v4.w * tj3.z - t4.w * vj3.z;
                    l.w += v4.w * tj3.w - t4.w * vj3.w;
                    *(float4*)Lp = l;
                }
            }
        }
        __syncthreads();   // trailing visible to next panel
    }

    if (tid == 0) {
        ws[bid * 2 + 0] = sgn;
        ws[bid * 2 + 1] = la;
    }
}

// ====================================================================
// Fallback (round-3 behavior): L in LDS, used only if ws is too small.
// ====================================================================
extern "C" __global__ __launch_bounds__(THREADS, 4)
void MultiPf_lds_fallback_kernel(const float* __restrict__ F,
                                 const int* __restrict__ idx,
                                 float* __restrict__ ws)
{
    extern __shared__ char smemc[];
    float* L      = (float*)smemc;                  // 33024 f (132096 B)
    float* Tcol   = (float*)(smemc + 132096);
    float* Vcol   = (float*)(smemc + 136192);
    float* TVrow  = (float*)(smemc + 140288);
    int*   idxL   = (int*)(smemc + 148480);

    const int tid = threadIdx.x;
    const int bid = blockIdx.x;
    const int b = bid >> 2;
    const int s = bid & 3;
    const float* __restrict__ Fs = F + (size_t)s * NFM * NFM;

    if (tid < NP) idxL[tid] = idx[b * NP + tid];
    __syncthreads();

    for (int e = tid; e < TRI; e += THREADS) {
        int r = (int)((1.0f + sqrtf(1.0f + 8.0f * (float)e)) * 0.5f);
        while (r * (r - 1) / 2 > e) --r;
        while (r * (r + 1) / 2 <= e) ++r;
        int c = e - r * (r - 1) / 2;
        int ir = idxL[r], ic = idxL[c];
        float val = 0.5f * (Fs[(size_t)ir * NFM + ic] - Fs[(size_t)ic * NFM + ir]);
        L[rowoff(r) + c] = val;
    }

    float sgn = 1.0f, la = 0.0f;
    __syncthreads();

    for (int kb = 0; kb < NP / BSTEPS; ++kb) {
        const int k0 = kb * BSTEPS;
        if (tid < 64) {
            const int lane = tid;
            for (int j = 0; j < NB; ++j) {
                const int k = k0 + 2 * j;
                const int p = k + 1;
                asm volatile("s_waitcnt lgkmcnt(0)" ::: "memory");
                __builtin_amdgcn_sched_barrier(0);
                float tk0 = 0.f, vk0 = 0.f, tk1 = 0.f, vk1 = 0.f, tk2 = 0.f, vk2 = 0.f;
                if (j > 0) { tk0 = Tcol[0 * NP + k]; vk0 = Vcol[0 * NP + k]; }
                if (j > 1) { tk1 = Tcol[1 * NP + k]; vk1 = Vcol[1 * NP + k]; }
                if (j > 2) { tk2 = Tcol[2 * NP + k]; vk2 = Vcol[2 * NP + k]; }
                float x[4];
                #pragma unroll
                for (int ii = 0; ii < 4; ++ii) {
                    const int r = lane + 64 * ii;
                    x[ii] = 0.0f;
                    if (r > k) {
                        const int orr = rowoff(r);
                        float xv = L[orr + k];
                        if (j > 0) xv += Vcol[0 * NP + r] * tk0 - Tcol[0 * NP + r] * vk0;
                        if (j > 1) xv += Vcol[1 * NP + r] * tk1 - Tcol[1 * NP + r] * vk1;
                        if (j > 2) xv += Vcol[2 * NP + r] * tk2 - Tcol[2 * NP + r] * vk2;
                        x[ii] = xv;
                    }
                }
                unsigned long long key = 0ull;
                #pragma unroll
                for (int ii = 0; ii < 4; ++ii) {
                    const int r = lane + 64 * ii;
                    if (r > k) {
                        const unsigned int bits = __float_as_uint(x[ii]);
                        const unsigned int ab = bits & 0x7fffffffu;
                        const unsigned long long kk =
                            ((unsigned long long)ab << 32) |
                            ((unsigned)(NP - 1 - r) << 1) | (bits >> 31);
                        if (kk > key) key = kk;
                    }
                }
                #pragma unroll
                for (int o = 1; o < 64; o <<= 1) {
                    const unsigned long long ok = __shfl_xor(key, o);
                    if (ok > key) key = ok;
                }
                const int kp = (NP - 1) - (int)((key >> 1) & 0xffu);
                const unsigned int csb =
                    (unsigned int)(key >> 32) | ((unsigned int)(key & 1u) << 31);
                const float cs = __uint_as_float(csb);
                const float piv = -cs;
                const float rpiv = 1.0f / piv;
                if (kp != p) sgn = -sgn;
                if (piv < 0.0f) sgn = -sgn;
                la += logf(fabsf(piv));
                const int slot = p >> 6, sl = p & 63;
                const float xsel = (slot == 0) ? x[0] : (slot == 1) ? x[1]
                                  : (slot == 2) ? x[2] : x[3];
                const float xp = __shfl(xsel, sl);
                float tp0 = 0.f, vp0 = 0.f, tp1 = 0.f, vp1 = 0.f, tp2 = 0.f, vp2 = 0.f;
                if (j > 0) { tp0 = Tcol[0 * NP + kp]; vp0 = Vcol[0 * NP + kp]; }
                if (j > 1) { tp1 = Tcol[1 * NP + kp]; vp1 = Vcol[1 * NP + kp]; }
                if (j > 2) { tp2 = Tcol[2 * NP + kp]; vp2 = Vcol[2 * NP + kp]; }
                float vsw[4];
                #pragma unroll
                for (int ii = 0; ii < 4; ++ii) vsw[ii] = 0.0f;
                if (kp == p) {
                    #pragma unroll
                    for (int ii = 0; ii < 4; ++ii) {
                        const int r = lane + 64 * ii;
                        if (r >= k + 2) vsw[ii] = L[rowoff(r) + p];
                    }
                } else {
                    const int okp = rowoff(kp);
                    #pragma unroll
                    for (int ii = 0; ii < 4; ++ii) {
                        const int r = lane + 64 * ii;
                        if (r >= k + 2) {
                            const int orr = rowoff(r);
                            if (r < kp) {
                                float a0 = L[orr + p], a1 = L[okp + r];
                                L[orr + p] = -a1; L[okp + r] = -a0;
                                vsw[ii] = -a1;
                            } else if (r == kp) {
                                float wv = -L[orr + p];
                                L[orr + p] = wv; vsw[ii] = wv;
                            } else {
                                float t = L[orr + p], u2 = L[orr + kp];
                                L[orr + p] = u2; L[orr + kp] = t;
                                vsw[ii] = u2;
                            }
                        }
                    }
                    if (lane < j) {
                        const int jj = lane;
                        float a, b2;
                        a = Tcol[jj * NP + p]; b2 = Tcol[jj * NP + kp];
                        Tcol[jj * NP + p] = b2; Tcol[jj * NP + kp] = a;
                        a = Vcol[jj * NP + p]; b2 = Vcol[jj * NP + kp];
                        Vcol[jj * NP + p] = b2; Vcol[jj * NP + kp] = a;
                        a = TVrow[p * 8 + jj]; b2 = TVrow[kp * 8 + jj];
                        TVrow[p * 8 + jj] = b2; TVrow[kp * 8 + jj] = a;
                        a = TVrow[p * 8 + 4 + jj]; b2 = TVrow[kp * 8 + 4 + jj];
                        TVrow[p * 8 + 4 + jj] = b2; TVrow[kp * 8 + 4 + jj] = a;
                    }
                }
                asm volatile("s_waitcnt lgkmcnt(0)" ::: "memory");
                __builtin_amdgcn_sched_barrier(0);
                #pragma unroll
                for (int ii = 0; ii < 4; ++ii) {
                    const int r = lane + 64 * ii;
                    if (r >= k + 2) {
                        const float xpost = (r == kp) ? xp : x[ii];
                        const float tau = xpost * rpiv;
                        float y = vsw[ii];
                        if (j > 0) y += Vcol[0 * NP + r] * tp0 - Tcol[0 * NP + r] * vp0;
                        if (j > 1) y += Vcol[1 * NP + r] * tp1 - Tcol[1 * NP + r] * vp1;
                        if (j > 2) y += Vcol[2 * NP + r] * tp2 - Tcol[2 * NP + r] * vp2;
                        Tcol[j * NP + r] = tau;
                        Vcol[j * NP + r] = y;
                        TVrow[r * 8 + j] = tau;
                        TVrow[r * 8 + 4 + j] = y;
                    }
                }
            }
        }
        __syncthreads();

        const int kend = k0 + BSTEPS;
        if (kend < NP) {
            const int w = tid >> 6;
            const int lane = tid & 63;
            const int c0 = kend + (lane << 2);
            float4 tj0 = {0,0,0,0}, tj1 = {0,0,0,0}, tj2 = {0,0,0,0}, tj3 = {0,0,0,0};
            float4 vj0 = {0,0,0,0}, vj1 = {0,0,0,0}, vj2 = {0,0,0,0}, vj3 = {0,0,0,0};
            if (c0 < NP) {
                tj0 = *(const float4*)(Tcol + 0 * NP + c0);
                tj1 = *(const float4*)(Tcol + 1 * NP + c0);
                tj2 = *(const float4*)(Tcol + 2 * NP + c0);
                tj3 = *(const float4*)(Tcol + 3 * NP + c0);
                vj0 = *(const float4*)(Vcol + 0 * NP + c0);
                vj1 = *(const float4*)(Vcol + 1 * NP + c0);
                vj2 = *(const float4*)(Vcol + 2 * NP + c0);
                vj3 = *(const float4*)(Vcol + 3 * NP + c0);
            }
            for (int r = kend + 1 + w; r < NP; r += NWAVES) {
                const float4 t4 = *(const float4*)(TVrow + r * 8);
                const float4 v4 = *(const float4*)(TVrow + r * 8 + 4);
                if (c0 < r) {
                    float* Lp = L + rowoff(r) + c0;
                    float4 l = *(float4*)Lp;
                    l.x += v4.x * tj0.x - t4.x * vj0.x;
                    l.y += v4.x * tj0.y - t4.x * vj0.y;
                    l.z += v4.x * tj0.z - t4.x * vj0.z;
                    l.w += v4.x * tj0.w - t4.x * vj0.w;
                    l.x += v4.y * tj1.x - t4.y * vj1.x;
                    l.y += v4.y * tj1.y - t4.y * vj1.y;
                    l.z += v4.y * tj1.z - t4.y * vj1.z;
                    l.w += v4.y * tj1.w - t4.y * vj1.w;
                    l.x += v4.z * tj2.x - t4.z * vj2.x;
                    l.y += v4.z * tj2.y - t4.z * vj2.y;
                    l.z += v4.z * tj2.z - t4.z * vj2.z;
                    l.w += v4.z * tj2.w - t4.z * vj2.w;
                    l.x += v4.w * tj3.x - t4.w * vj3.x;
                    l.y += v4.w * tj3.y - t4.w * vj3.y;
                    l.z += v4.w * tj3.z - t4.w * vj3.z;
                    l.w += v4.w * tj3.w - t4.w * vj3.w;
                    *(float4*)Lp = l;
                }
            }
        }
        __syncthreads();
    }

    if (tid == 0) {
        ws[bid * 2 + 0] = sgn;
        ws[bid * 2 + 1] = la;
    }
}

extern "C" __global__ void MultiPf_combine_kernel(const float* __restrict__ ws,
                                                  float* __restrict__ out)
{
    int b = threadIdx.x + blockIdx.x * blockDim.x;
    if (b >= BATCH) return;
    float sg[NPFS], lg[NPFS];
    float m = -INFINITY;
    for (int j = 0; j < NPFS; ++j) {
        sg[j] = ws[(b * NPFS + j) * 2 + 0];
        lg[j] = ws[(b * NPFS + j) * 2 + 1];
        m = fmaxf(m, lg[j]);
    }
    float val = 0.0f;
    for (int j = 0; j < NPFS; ++j)
        val += sg[j] * expf(lg[j] - m);
    float osgn = (val > 0.0f) ? 1.0f : ((val < 0.0f) ? -1.0f : 0.0f);
    out[b]         = osgn;
    out[BATCH + b] = m + logf(fabsf(val));
}

extern "C" void kernel_launch(void* const* d_in, const int* in_sizes, int n_in,
                              void* d_out, int out_size, void* d_ws, size_t ws_size,
                              hipStream_t stream)
{
    (void)in_sizes; (void)n_in; (void)out_size;
    const float* F   = (const float*)d_in[0];
    const int*   idx = (const int*)d_in[1];
    float* out = (float*)d_out;
    float* ws  = (float*)d_ws;

    // workspace needed for the global-L version:
    // 1024 result floats + 512 blocks * 33024 floats
    const size_t need = (1024 + (size_t)NBLK * LFLOATS) * sizeof(float);

    if (ws_size >= need) {
        MultiPf_32469952758284_kernel<<<NBLK, THREADS, 0, stream>>>(F, idx, ws);
    } else {
        const size_t smem_bytes = 149504;
        (void)hipFuncSetAttribute((const void*)MultiPf_lds_fallback_kernel,
                                  hipFuncAttributeMaxDynamicSharedMemorySize,
                                  (int)smem_bytes);
        MultiPf_lds_fallback_kernel<<<NBLK, THREADS, smem_bytes, stream>>>(F, idx, ws);
    }
    MultiPf_combine_kernel<<<1, 128, 0, stream>>>(ws, out);
}

// Round 6
// 567.233 us; speedup vs baseline: 1.9097x; 1.9097x over previous
//
#include <hip/hip_runtime.h>
#include <math.h>

#define NPFS   4
#define NFM    512
#define NP     256
#define BATCH  128
#define NBLK   (BATCH * NPFS)   // 512 pfaffians
#define THREADS 1024
#define NWAVES (THREADS / 64)
#define TRI    ((NP * (NP - 1)) / 2)   // 32640 strict-lower elements
#define NB     4                 // steps per panel block -> rank-8 trailing update
#define BSTEPS (2 * NB)          // 8 columns consumed per block

// fp32 packed strict-lower triangle, each row padded to a multiple of 4
// floats so every row starts 16B-aligned. rowoff(256) = 33024 floats.
__device__ __forceinline__ int rowoff(int r) {
    int q = r >> 2, rem = r & 3;
    int g = 2 * q * q + q;
    if (rem > 0) g += q;
    if (rem > 1) g += q + 1;
    if (rem > 2) g += q + 1;
    return g << 2;
}

extern "C" __global__ __launch_bounds__(THREADS, 4)
void MultiPf_32469952758284_kernel(const float* __restrict__ F,
                                   const int* __restrict__ idx,
                                   float* __restrict__ ws)
{
    extern __shared__ char smemc[];
    float* L      = (float*)smemc;                  // 33024 f (132096 B)
    float* Tcol   = (float*)(smemc + 132096);       // NB*256 f (tau_j, col-major)
    float* Vcol   = (float*)(smemc + 136192);       // NB*256 f (v_j, col-major)
    float* TVrow  = (float*)(smemc + 140288);       // 256*8 f  (row-major dup: t0..3,v0..3)
    float* colbuf = (float*)(smemc + 148480);       // 256 f (current pivot column)
    int*   idxL   = (int*)(smemc + 149504);         // 256
    // total 150528 B (one block/CU; 16 waves)

    const int tid = threadIdx.x;
    const int bid = blockIdx.x;
    const int b = bid >> 2;   // batch
    const int s = bid & 3;    // pf-state
    const float* __restrict__ Fs = F + (size_t)s * NFM * NFM;

    if (tid < NP) idxL[tid] = idx[b * NP + tid];
    __syncthreads();

    // ---- gather strict lower triangle: A[r][c] = 0.5*(F[ir][ic] - F[ic][ir])
    // Also seed colbuf with column 0 for the first pivot search.
    for (int e = tid; e < TRI; e += THREADS) {
        int r = (int)((1.0f + sqrtf(1.0f + 8.0f * (float)e)) * 0.5f);
        while (r * (r - 1) / 2 > e) --r;
        while (r * (r + 1) / 2 <= e) ++r;
        int c = e - r * (r - 1) / 2;
        int ir = idxL[r], ic = idxL[c];
        float val = 0.5f * (Fs[(size_t)ir * NFM + ic] - Fs[(size_t)ic * NFM + ir]);
        L[rowoff(r) + c] = val;
        if (c == 0) colbuf[r] = val;
    }

    float sgn = 1.0f, la = 0.0f;   // maintained on tid<NP; tid 0 writes out
    __syncthreads();

    for (int kb = 0; kb < NP / BSTEPS; ++kb) {
        const int k0 = kb * BSTEPS;

        // ================= panel: NB steps, lazy trailing =================
        for (int j = 0; j < NB; ++j) {
            const int k = k0 + 2 * j;
            const int p = k + 1;

            // ---- A1 (j>0): refresh column k with pending in-block terms
            //      into colbuf only (column k of L is consumed this step —
            //      no write-back needed; round-3-proven equivalence).
            //      j==0: trailing/gather already left colbuf fresh.
            if (j > 0) {
                if (tid > k && tid < NP) {
                    const int r = tid;
                    const int orr = rowoff(r);
                    float x = L[orr + k];
                    for (int jj = 0; jj < j; ++jj) {
                        const float tk  = Tcol[jj * NP + k];
                        const float vk  = Vcol[jj * NP + k];
                        const float tr_ = Tcol[jj * NP + r];
                        const float vr_ = Vcol[jj * NP + r];
                        x += vr_ * tk - tr_ * vk;
                    }
                    colbuf[r] = x;
                }
                __syncthreads();   // B1
            }

            // ---- argmax + P2 swap (single phase; waves 0-3 redundant)
            int kp = 0; float rpiv = 0.0f;
            if (tid < NP) {
                const int lane = tid & 63;
                const int base = lane << 2;
                // each wave reads the whole column: lane holds rows 4l..4l+3
                const float4 c4 = *(const float4*)(colbuf + base);
                const float xs[4] = {c4.x, c4.y, c4.z, c4.w};
                // wave max of |x| bits over valid rows (32-bit, 6 hops)
                unsigned km = 0u;
                #pragma unroll
                for (int e = 0; e < 4; ++e) {
                    const int r2 = base + e;
                    const unsigned ab = __float_as_uint(xs[e]) & 0x7fffffffu;
                    if (r2 > k && ab > km) km = ab;
                }
                #pragma unroll
                for (int o = 1; o < 64; o <<= 1) {
                    const unsigned ov = (unsigned)__shfl_xor((int)km, o);
                    if (ov > km) km = ov;
                }
                // lowest row holding the max (exact jnp.argmax tie order)
                int cand = 0x7fffffff;
                #pragma unroll
                for (int e = 0; e < 4; ++e) {
                    const int r2 = base + e;
                    const bool c = (r2 > k) &&
                        ((__float_as_uint(xs[e]) & 0x7fffffffu) == km);
                    const unsigned long long mb = __ballot(c);
                    if (mb) {
                        const int rr = ((int)__builtin_ctzll(mb) << 2) + e;
                        if (rr < cand) cand = rr;
                    }
                }
                kp = cand;
                const float cs = colbuf[kp];   // broadcast re-read
                const float piv = -cs;         // piv = A_post[k][k+1] = -L_pre[kp][k]
                rpiv = 1.0f / piv;
                if (kp != p) sgn = -sgn;
                if (piv < 0.0f) sgn = -sgn;
                la += logf(fabsf(piv));

                // P2: symmetric swap p<->kp on L (live region only; thread r
                // owns exactly the elements it touches). Column-k swap dropped:
                // column k is dead (tau comes from colbuf).
                const int r = tid;
                if (kp != p) {
                    if (r >= k + 2) {
                        const int orr = rowoff(r);
                        if (r < kp) {
                            const int okp = rowoff(kp);
                            float a0 = L[orr + p], a1 = L[okp + r];
                            L[orr + p] = -a1; L[okp + r] = -a0;
                        } else if (r == kp) {
                            L[orr + p] = -L[orr + p];   // (kp,p) negates
                        } else { // r > kp
                            float t = L[orr + p];
                            L[orr + p] = L[orr + kp]; L[orr + kp] = t;
                        }
                    }
                    // physical swap of rows p,kp in accumulated panels (jj<j),
                    // done by otherwise-idle threads jj (< j <= 3 < k+2).
                    if (tid < j) {
                        const int jj = tid;
                        float a, b2;
                        a = Tcol[jj * NP + p]; b2 = Tcol[jj * NP + kp];
                        Tcol[jj * NP + p] = b2; Tcol[jj * NP + kp] = a;
                        a = Vcol[jj * NP + p]; b2 = Vcol[jj * NP + kp];
                        Vcol[jj * NP + p] = b2; Vcol[jj * NP + kp] = a;
                        a = TVrow[p * 8 + jj]; b2 = TVrow[kp * 8 + jj];
                        TVrow[p * 8 + jj] = b2; TVrow[kp * 8 + jj] = a;
                        a = TVrow[p * 8 + 4 + jj]; b2 = TVrow[kp * 8 + 4 + jj];
                        TVrow[p * 8 + 4 + jj] = b2; TVrow[kp * 8 + 4 + jj] = a;
                    }
                }
            }
            __syncthreads();   // B2

            // ---- A2: refresh column p (post-swap) + extract tau/v into panels.
            // tau source: colbuf (refreshed col k); row kp post-swap holds
            // pre-swap row p => colbuf[p].
            if (tid < NP) {
                const int r = tid;
                float tau = 0.0f, vv = 0.0f;
                if (r >= k + 2) {
                    const int orr = rowoff(r);
                    tau = colbuf[(r == kp) ? p : r] * rpiv;
                    float y = L[orr + p];
                    for (int jj = 0; jj < j; ++jj) {
                        const float tp_ = Tcol[jj * NP + p];   // post-swap rows
                        const float vp_ = Vcol[jj * NP + p];
                        const float tr_ = Tcol[jj * NP + r];
                        const float vr_ = Vcol[jj * NP + r];
                        y += vr_ * tp_ - tr_ * vp_;
                    }
                    vv = y;
                }
                Tcol[j * NP + r] = tau;
                Vcol[j * NP + r] = vv;
                TVrow[r * 8 + j] = tau;
                TVrow[r * 8 + 4 + j] = vv;
            }
            __syncthreads();   // B3
        }

        // ================= trailing rank-2*NB update =================
        // Lane owns 4 FIXED columns -> tau/v column values preloaded into
        // registers once per block. Per row: 1 b128 read + 1 b128 write of L
        // + 2 uniform b128 broadcasts (TVrow). Captures column kend -> colbuf.
        const int kend = k0 + BSTEPS;   // multiple of 8 -> 16B aligned
        if (kend < NP) {
            const int w = tid >> 6;
            const int lane = tid & 63;
            const int c0 = kend + (lane << 2);
            float4 tj0 = {0,0,0,0}, tj1 = {0,0,0,0}, tj2 = {0,0,0,0}, tj3 = {0,0,0,0};
            float4 vj0 = {0,0,0,0}, vj1 = {0,0,0,0}, vj2 = {0,0,0,0}, vj3 = {0,0,0,0};
            if (c0 < NP) {
                tj0 = *(const float4*)(Tcol + 0 * NP + c0);
                tj1 = *(const float4*)(Tcol + 1 * NP + c0);
                tj2 = *(const float4*)(Tcol + 2 * NP + c0);
                tj3 = *(const float4*)(Tcol + 3 * NP + c0);
                vj0 = *(const float4*)(Vcol + 0 * NP + c0);
                vj1 = *(const float4*)(Vcol + 1 * NP + c0);
                vj2 = *(const float4*)(Vcol + 2 * NP + c0);
                vj3 = *(const float4*)(Vcol + 3 * NP + c0);
            }
            for (int r = kend + 1 + w; r < NP; r += NWAVES) {
                const float4 t4 = *(const float4*)(TVrow + r * 8);      // tau_j[r]
                const float4 v4 = *(const float4*)(TVrow + r * 8 + 4);  // v_j[r]
                if (c0 < r) {
                    float* Lp = L + rowoff(r) + c0;
                    float4 l = *(float4*)Lp;
                    // jj ascending: same per-element rounding chain as reference
                    l.x += v4.x * tj0.x - t4.x * vj0.x;
                    l.y += v4.x * tj0.y - t4.x * vj0.y;
                    l.z += v4.x * tj0.z - t4.x * vj0.z;
                    l.w += v4.x * tj0.w - t4.x * vj0.w;
                    l.x += v4.y * tj1.x - t4.y * vj1.x;
                    l.y += v4.y * tj1.y - t4.y * vj1.y;
                    l.z += v4.y * tj1.z - t4.y * vj1.z;
                    l.w += v4.y * tj1.w - t4.y * vj1.w;
                    l.x += v4.z * tj2.x - t4.z * vj2.x;
                    l.y += v4.z * tj2.y - t4.z * vj2.y;
                    l.z += v4.z * tj2.z - t4.z * vj2.z;
                    l.w += v4.z * tj2.w - t4.z * vj2.w;
                    l.x += v4.w * tj3.x - t4.w * vj3.x;
                    l.y += v4.w * tj3.y - t4.w * vj3.y;
                    l.z += v4.w * tj3.z - t4.w * vj3.z;
                    l.w += v4.w * tj3.w - t4.w * vj3.w;
                    *(float4*)Lp = l;
                    if (lane == 0) colbuf[r] = l.x;   // column kend for next argmax
                }
            }
        }
        __syncthreads();   // trailing + colbuf visible to next panel
    }

    if (tid == 0) {
        ws[bid * 2 + 0] = sgn;
        ws[bid * 2 + 1] = la;
    }
}

extern "C" __global__ void MultiPf_combine_kernel(const float* __restrict__ ws,
                                                  float* __restrict__ out)
{
    int b = threadIdx.x + blockIdx.x * blockDim.x;
    if (b >= BATCH) return;
    float sg[NPFS], lg[NPFS];
    float m = -INFINITY;
    for (int j = 0; j < NPFS; ++j) {
        sg[j] = ws[(b * NPFS + j) * 2 + 0];
        lg[j] = ws[(b * NPFS + j) * 2 + 1];
        m = fmaxf(m, lg[j]);
    }
    float val = 0.0f;
    for (int j = 0; j < NPFS; ++j)
        val += sg[j] * expf(lg[j] - m);
    float osgn = (val > 0.0f) ? 1.0f : ((val < 0.0f) ? -1.0f : 0.0f);
    out[b]         = osgn;
    out[BATCH + b] = m + logf(fabsf(val));
}

extern "C" void kernel_launch(void* const* d_in, const int* in_sizes, int n_in,
                              void* d_out, int out_size, void* d_ws, size_t ws_size,
                              hipStream_t stream)
{
    (void)in_sizes; (void)n_in; (void)out_size; (void)ws_size;
    const float* F   = (const float*)d_in[0];
    const int*   idx = (const int*)d_in[1];
    float* out = (float*)d_out;
    float* ws  = (float*)d_ws;

    const size_t smem_bytes = 150528;   // see LDS layout in kernel

    // Raise dynamic-LDS cap above the 64 KB default (gfx950: 160 KB/CU).
    (void)hipFuncSetAttribute((const void*)MultiPf_32469952758284_kernel,
                              hipFuncAttributeMaxDynamicSharedMemorySize,
                              (int)smem_bytes);

    MultiPf_32469952758284_kernel<<<NBLK, THREADS, smem_bytes, stream>>>(F, idx, ws);
    MultiPf_combine_kernel<<<1, 128, 0, stream>>>(ws, out);
}